// Round 9
// baseline (347.437 us; speedup 1.0000x reference)
//
#include <hip/hip_runtime.h>

#define MEM    150
#define GW     640   // 4 gates interleaved: col = 4*j + g  (g: 0=i,1=f,2=u,3=o)
#define KX     300   // x-proj real K
#define KXP    320   // x-proj padded K (bf16 A buffer pitch)
#define KH     160   // level GEMM K (padded, H buffer is pre-padded)
#define NLEAF  65536
#define NTOT   87381
#define DEPTH  9

static const int SIZES[DEPTH] = {65536,16384,4096,1024,256,64,16,4,1};
static const int OFF[DEPTH]   = {0,65536,81920,86016,87040,87296,87360,87376,87380};

typedef __attribute__((ext_vector_type(8))) short short8;
typedef __attribute__((ext_vector_type(4))) float f32x4;

__device__ __forceinline__ float sigf(float x) { return 1.0f / (1.0f + __expf(-x)); }
__device__ __forceinline__ float tanhf_fast(float x) {
    float e = __expf(2.0f * x);
    return 1.0f - 2.0f / (e + 1.0f);
}
__device__ __forceinline__ unsigned short f2bf(float f) {
    union { float f; unsigned u; } v; v.f = f;
    unsigned r = v.u + 0x7FFF + ((v.u >> 16) & 1);
    return (unsigned short)(r >> 16);
}
__device__ __forceinline__ float bf2f(unsigned short u) {
    union { unsigned u; float f; } v; v.u = ((unsigned)u) << 16; return v.f;
}

// async global->LDS, 16 bytes per lane
typedef const __attribute__((address_space(1))) unsigned int* as1_u32p;
typedef __attribute__((address_space(3))) unsigned int* as3_u32p;
__device__ __forceinline__ void gl_lds16(const unsigned short* g, unsigned short* l) {
    __builtin_amdgcn_global_load_lds((as1_u32p)g, (as3_u32p)l, 16, 0, 0);
}

// ---------------- prep: weight packing + embs conversion (one dispatch) --------
__global__ void prep(const float* __restrict__ Wix, const float* __restrict__ Wfx,
                     const float* __restrict__ Wux, const float* __restrict__ Wox,
                     const float* __restrict__ bix, const float* __restrict__ bfx,
                     const float* __restrict__ bux, const float* __restrict__ box,
                     const float* __restrict__ Wih, const float* __restrict__ Wfh,
                     const float* __restrict__ Wuh, const float* __restrict__ Woh,
                     const float* __restrict__ bfh,
                     const float* __restrict__ embs,
                     unsigned short* __restrict__ W4xT, unsigned short* __restrict__ W4hT,
                     float* __restrict__ b4x, float* __restrict__ b4hf,
                     unsigned short* __restrict__ Abf)
{
    if (blockIdx.x < 256) {
        int tid = blockIdx.x * 256 + threadIdx.x;
        const int stride = 256 * 256;
        for (int idx = tid; idx < GW * KXP; idx += stride) {
            int c = idx / KXP, k = idx - c * KXP;
            int j = c >> 2, g = c & 3;
            const float* W = (g == 0) ? Wix : (g == 1) ? Wfx : (g == 2) ? Wux : Wox;
            W4xT[idx] = (j < MEM && k < KX) ? f2bf(W[k * MEM + j]) : (unsigned short)0;
        }
        for (int idx = tid; idx < GW * KH; idx += stride) {
            int c = idx / KH, k = idx - c * KH;
            int j = c >> 2, g = c & 3;
            const float* W = (g == 0) ? Wih : (g == 1) ? Wfh : (g == 2) ? Wuh : Woh;
            W4hT[idx] = (j < MEM && k < MEM) ? f2bf(W[k * MEM + j]) : (unsigned short)0;
        }
        for (int idx = tid; idx < GW; idx += stride) {
            int j = idx >> 2, g = idx & 3;
            const float* b = (g == 0) ? bix : (g == 1) ? bfx : (g == 2) ? bux : box;
            b4x[idx]  = (j < MEM) ? b[j] : 0.0f;
            b4hf[idx] = (g == 1 && j < MEM) ? bfh[j] : 0.0f;
        }
    } else {
        int idx = (blockIdx.x - 256) * 256 + threadIdx.x;
        if (idx >= NTOT * (KXP / 8)) return;
        int n = idx / (KXP / 8), c = idx - n * (KXP / 8);
        int c0 = c * 8;
        unsigned short v[8];
        if (c0 + 8 <= KX) {
            const float4* p = (const float4*)(embs + (size_t)n * KX + c0);
            float4 f0 = p[0], f1 = p[1];
            v[0]=f2bf(f0.x); v[1]=f2bf(f0.y); v[2]=f2bf(f0.z); v[3]=f2bf(f0.w);
            v[4]=f2bf(f1.x); v[5]=f2bf(f1.y); v[6]=f2bf(f1.z); v[7]=f2bf(f1.w);
        } else {
            const float* row = embs + (size_t)n * KX;
            #pragma unroll
            for (int j = 0; j < 8; ++j) {
                int col = c0 + j;
                v[j] = (col < KX) ? f2bf(row[col]) : (unsigned short)0;
            }
        }
        *(short8*)&Abf[(size_t)n * KXP + c0] = *(short8*)v;
    }
}

// ---------------- x-proj GEMM: 512 thr, 3-buffer 2-ahead pipeline --------------
// Tile 128x128, BK=32, 3 LDS buffer sets (48KB). Per K-step: issue stage kt+2
// -> s_waitcnt vmcnt(4) (stage kt landed; kt+1,kt+2 stay in flight across the
// MFMA phase + 2 barriers = ~2x hiding of the 2-buffer version) -> barrier ->
// ds_read+MFMA -> barrier. Chunk swizzle uses (row ^ row>>2)&3 on BOTH the
// staging source and the read (rule #21): read-side bank conflict 4-way -> 2-way
// (free). Occupancy cap 3 blocks/CU (75%) vs measured ~53% -> no loss.
__global__ __launch_bounds__(512) void gemm_xproj(
    const unsigned short* __restrict__ A,
    const unsigned short* __restrict__ BT,
    const float* __restrict__ bias,
    unsigned short* __restrict__ PG,
    const float* __restrict__ bih, const float* __restrict__ buh,
    const float* __restrict__ boh,
    float* __restrict__ outLeaf, float* __restrict__ CLeaf,
    unsigned short* __restrict__ HbfLeaf)
{
    __shared__ __align__(16) unsigned short lds[24576];   // As[3]|Bs[3]; epi reuses [0,16384)
    unsigned short* As = lds;            // 3 x 4096
    unsigned short* Bs = lds + 12288;    // 3 x 4096

    // bijective XCD swizzle (m204)
    const int nwg = gridDim.x;
    const int orig = blockIdx.x;
    const int qq = nwg >> 3, rr = nwg & 7;
    const int xcd = orig & 7, lin = orig >> 3;
    const int dd = (xcd < rr ? xcd * (qq + 1) : rr * (qq + 1) + (xcd - rr) * qq) + lin;
    const int mtile = dd / 5, ntile = dd - mtile * 5;

    const int t = threadIdx.x;
    const int m0 = mtile * 128, n0 = ntile * 128;
    const int l = t & 63, w = t >> 6;            // 8 waves
    const int l15 = l & 15, q = l >> 4;
    const int wm = (w & 1) * 64, wn = (w >> 1) * 32;

    // staging: thread t -> LDS chunk (row=t>>2, c=t&3); SOURCE chunk is
    // (t&3) ^ ((row ^ row>>2)&3)  — involution, both-sides with the read.
    const int srow = t >> 2;
    const int sx = (srow ^ (srow >> 2)) & 3;
    const int scol = ((t & 3) ^ sx) * 8;
    int gr0 = m0 + srow; if (gr0 >= NTOT) gr0 = NTOT - 1;
    const unsigned short* a0 = A + (size_t)gr0 * KXP + scol;
    const unsigned short* b0 = BT + (size_t)(n0 + srow) * KXP + scol;

    f32x4 acc[4][2];
    #pragma unroll
    for (int i = 0; i < 4; ++i)
        #pragma unroll
        for (int j = 0; j < 2; ++j)
            acc[i][j] = (f32x4){0.f, 0.f, 0.f, 0.f};

    const int NST = KXP >> 5;   // 10
    // prologue: stages 0,1
    gl_lds16(a0,      As + t * 8);
    gl_lds16(b0,      Bs + t * 8);
    gl_lds16(a0 + 32, As + 4096 + t * 8);
    gl_lds16(b0 + 32, Bs + 4096 + t * 8);

    // read-side de-swizzled chunk: q ^ (l15&3) ^ (l15>>2)  (rows are base+l15,
    // base multiple of 16 -> row bits reduce to l15 bits)
    const int csw = ((q ^ (l15 & 3) ^ (l15 >> 2)) & 3) * 8;

    #pragma unroll
    for (int kt = 0; kt < NST; ++kt) {
        if (kt + 2 < NST) {
            const int s = kt + 2;
            const int bi = s - (s / 3) * 3;            // s % 3 (constant-folded)
            gl_lds16(a0 + s * 32, As + bi * 4096 + t * 8);
            gl_lds16(b0 + s * 32, Bs + bi * 4096 + t * 8);
            __builtin_amdgcn_sched_barrier(0);          // pin issue before wait
            asm volatile("s_waitcnt vmcnt(4)" ::: "memory");   // stage kt landed
        } else if (kt + 1 < NST) {
            asm volatile("s_waitcnt vmcnt(2)" ::: "memory");
        } else {
            asm volatile("s_waitcnt vmcnt(0)" ::: "memory");
        }
        __builtin_amdgcn_s_barrier();
        __builtin_amdgcn_sched_barrier(0);              // rule #18: no hoist

        const int cb = kt - (kt / 3) * 3;               // kt % 3
        short8 a[4], b[2];
        #pragma unroll
        for (int i = 0; i < 4; ++i)
            a[i] = *(const short8*)&As[cb * 4096 + (wm + i * 16 + l15) * 32 + csw];
        #pragma unroll
        for (int j = 0; j < 2; ++j)
            b[j] = *(const short8*)&Bs[cb * 4096 + (wn + j * 16 + l15) * 32 + csw];
        __builtin_amdgcn_s_setprio(1);
        #pragma unroll
        for (int i = 0; i < 4; ++i)
            #pragma unroll
            for (int j = 0; j < 2; ++j)
                acc[i][j] = __builtin_amdgcn_mfma_f32_16x16x32_bf16(a[i], b[j], acc[i][j], 0, 0, 0);
        __builtin_amdgcn_s_setprio(0);
        __builtin_amdgcn_sched_barrier(0);              // keep reads in phase
        __builtin_amdgcn_s_barrier();                   // buffer-reuse guard
    }

    // ---- epilogue: bias + bf16 into LDS tile [128][128] (first 32KB) ----
    float bj[2];
    #pragma unroll
    for (int j = 0; j < 2; ++j) bj[j] = bias[n0 + wn + j * 16 + l15];
    #pragma unroll
    for (int i = 0; i < 4; ++i)
        #pragma unroll
        for (int j = 0; j < 2; ++j)
            #pragma unroll
            for (int r = 0; r < 4; ++r)
                lds[(wm + i * 16 + q * 4 + r) * 128 + wn + j * 16 + l15] =
                    f2bf(acc[i][j][r] + bj[j]);
    __syncthreads();

    if (m0 < NLEAF) {
        // leaf LSTM cell: tile holds cols 4*j+g for j in [32*ntile, +32)
        #pragma unroll
        for (int s = 0; s < 8; ++s) {
            int idx = (s << 9) + t;
            int row = idx >> 5, jl = idx & 31;
            int grow = m0 + row;
            int j = ntile * 32 + jl;
            const unsigned short* g4 = &lds[row * 128 + jl * 4];
            if (j < MEM) {
                float gi = bf2f(g4[0]) + bih[j];
                float gu = bf2f(g4[2]) + buh[j];
                float go = bf2f(g4[3]) + boh[j];
                float iv = sigf(gi), uv = tanhf_fast(gu), ov = sigf(go);
                float c = iv * uv;
                float h = ov * tanhf_fast(c);
                outLeaf[(size_t)grow * MEM + j] = h;
                CLeaf[(size_t)grow * MEM + j] = c;
                HbfLeaf[(size_t)grow * KH + j] = f2bf(h);
            } else if (j < KH) {
                HbfLeaf[(size_t)grow * KH + j] = 0;
            }
        }
    } else {
        int row = t >> 2, qd = t & 3;
        int grow = m0 + row;
        if (grow < NTOT) {
            const unsigned short* src = &lds[row * 128 + qd * 32];
            unsigned short* dst = PG + (size_t)grow * GW + n0 + qd * 32;
            #pragma unroll
            for (int c8 = 0; c8 < 4; ++c8)
                *(short8*)(dst + c8 * 8) = *(const short8*)(src + c8 * 8);
        }
    }
}

// ---------------- level GEMM: 512 thr, 3-buffer pipeline + fused cell ----------
__global__ __launch_bounds__(512) void gemm_level(
    const unsigned short* __restrict__ Hprev, int nprev, int npar,
    const unsigned short* __restrict__ BT, const float* __restrict__ bias,
    const unsigned short* __restrict__ P,     // this level's x-proj rows
    const float* __restrict__ Cprev,
    const float* __restrict__ bih, const float* __restrict__ buh,
    const float* __restrict__ boh,
    float* __restrict__ outRow, float* __restrict__ Crow,
    unsigned short* __restrict__ HbfRow)
{
    __shared__ __align__(16) unsigned short lds[24576];
    unsigned short* As = lds;
    unsigned short* Bs = lds + 12288;

    const int nwg = gridDim.x;
    const int orig = blockIdx.x;
    const int qq = nwg >> 3, rr = nwg & 7;
    const int xcd = orig & 7, lin = orig >> 3;
    const int dd = (xcd < rr ? xcd * (qq + 1) : rr * (qq + 1) + (xcd - rr) * qq) + lin;
    const int mtile = dd / 5, ntile = dd - mtile * 5;

    const int t = threadIdx.x;
    const int m0 = mtile * 128, n0 = ntile * 128;
    const int l = t & 63, w = t >> 6;
    const int l15 = l & 15, q = l >> 4;
    const int wm = (w & 1) * 64, wn = (w >> 1) * 32;

    const int srow = t >> 2;
    const int sx = (srow ^ (srow >> 2)) & 3;
    const int scol = ((t & 3) ^ sx) * 8;
    int gr0 = m0 + srow; if (gr0 >= nprev) gr0 = nprev - 1;
    const unsigned short* a0 = Hprev + (size_t)gr0 * KH + scol;
    const unsigned short* b0 = BT + (size_t)(n0 + srow) * KH + scol;

    f32x4 acc[4][2];
    #pragma unroll
    for (int i = 0; i < 4; ++i)
        #pragma unroll
        for (int j = 0; j < 2; ++j)
            acc[i][j] = (f32x4){0.f, 0.f, 0.f, 0.f};

    const int NST = KH >> 5;   // 5
    gl_lds16(a0,      As + t * 8);
    gl_lds16(b0,      Bs + t * 8);
    gl_lds16(a0 + 32, As + 4096 + t * 8);
    gl_lds16(b0 + 32, Bs + 4096 + t * 8);

    const int csw = ((q ^ (l15 & 3) ^ (l15 >> 2)) & 3) * 8;

    #pragma unroll
    for (int kt = 0; kt < NST; ++kt) {
        if (kt + 2 < NST) {
            const int s = kt + 2;
            const int bi = s - (s / 3) * 3;
            gl_lds16(a0 + s * 32, As + bi * 4096 + t * 8);
            gl_lds16(b0 + s * 32, Bs + bi * 4096 + t * 8);
            __builtin_amdgcn_sched_barrier(0);
            asm volatile("s_waitcnt vmcnt(4)" ::: "memory");
        } else if (kt + 1 < NST) {
            asm volatile("s_waitcnt vmcnt(2)" ::: "memory");
        } else {
            asm volatile("s_waitcnt vmcnt(0)" ::: "memory");
        }
        __builtin_amdgcn_s_barrier();
        __builtin_amdgcn_sched_barrier(0);

        const int cb = kt - (kt / 3) * 3;
        short8 a[4], b[2];
        #pragma unroll
        for (int i = 0; i < 4; ++i)
            a[i] = *(const short8*)&As[cb * 4096 + (wm + i * 16 + l15) * 32 + csw];
        #pragma unroll
        for (int j = 0; j < 2; ++j)
            b[j] = *(const short8*)&Bs[cb * 4096 + (wn + j * 16 + l15) * 32 + csw];
        __builtin_amdgcn_s_setprio(1);
        #pragma unroll
        for (int i = 0; i < 4; ++i)
            #pragma unroll
            for (int j = 0; j < 2; ++j)
                acc[i][j] = __builtin_amdgcn_mfma_f32_16x16x32_bf16(a[i], b[j], acc[i][j], 0, 0, 0);
        __builtin_amdgcn_s_setprio(0);
        __builtin_amdgcn_sched_barrier(0);
        __builtin_amdgcn_s_barrier();
    }

    // ---- per-child preacts (bf16, f-bias applied) into LDS tile [128][128] ----
    float bj[2];
    #pragma unroll
    for (int j = 0; j < 2; ++j) bj[j] = bias[n0 + wn + j * 16 + l15];
    #pragma unroll
    for (int i = 0; i < 4; ++i)
        #pragma unroll
        for (int j = 0; j < 2; ++j)
            #pragma unroll
            for (int r = 0; r < 4; ++r)
                lds[(wm + i * 16 + q * 4 + r) * 128 + wn + j * 16 + l15] =
                    f2bf(acc[i][j][r] + bj[j]);
    __syncthreads();

    // ---- fused cell: 32 parents x 32 features per block ----
    const int pp0 = m0 >> 2;
    #pragma unroll
    for (int s = 0; s < 2; ++s) {
        int idx = (s << 9) + t;          // 0..1023
        int pl = idx >> 5, jl = idx & 31;
        int par = pp0 + pl;
        if (par >= npar) continue;
        int j = ntile * 32 + jl;
        if (j < MEM) {
            const unsigned short* xr = P + (size_t)par * GW + 4 * j;
            float ip = bf2f(xr[0]) + bih[j];
            float fx = bf2f(xr[1]);
            float up = bf2f(xr[2]) + buh[j];
            float op = bf2f(xr[3]) + boh[j];
            float fc = 0.0f;
            #pragma unroll
            for (int k = 0; k < 4; ++k) {
                const unsigned short* g4 = &lds[(pl * 4 + k) * 128 + jl * 4];
                ip += bf2f(g4[0]);
                up += bf2f(g4[2]);
                op += bf2f(g4[3]);
                float f = sigf(fx + bf2f(g4[1]));
                fc += f * Cprev[(size_t)(4 * par + k) * MEM + j];
            }
            float iv = sigf(ip), uv = tanhf_fast(up), ov = sigf(op);
            float c = iv * uv + fc;
            float h = ov * tanhf_fast(c);
            outRow[(size_t)par * MEM + j] = h;
            Crow[(size_t)par * MEM + j] = c;
            HbfRow[(size_t)par * KH + j] = f2bf(h);
        } else if (j < KH) {
            HbfRow[(size_t)par * KH + j] = 0;
        }
    }
}

extern "C" void kernel_launch(void* const* d_in, const int* in_sizes, int n_in,
                              void* d_out, int out_size, void* d_ws, size_t ws_size,
                              hipStream_t stream)
{
    (void)in_sizes; (void)n_in; (void)out_size;
    const float* embs = (const float*)d_in[0];
    const float* Wix = (const float*)d_in[1];  const float* bix = (const float*)d_in[2];
    const float* Wfx = (const float*)d_in[3];  const float* bfx = (const float*)d_in[4];
    const float* Wux = (const float*)d_in[5];  const float* bux = (const float*)d_in[6];
    const float* Wox = (const float*)d_in[7];  const float* box = (const float*)d_in[8];
    const float* Wih = (const float*)d_in[9];  const float* bih = (const float*)d_in[10];
    const float* Wfh = (const float*)d_in[11]; const float* bfh = (const float*)d_in[12];
    const float* Wuh = (const float*)d_in[13]; const float* buh = (const float*)d_in[14];
    const float* Woh = (const float*)d_in[15]; const float* boh = (const float*)d_in[16];
    float* out = (float*)d_out;

    char* p = (char*)d_ws;
    auto alloc = [&](size_t bytes) -> char* {
        char* r = p;
        p += (bytes + 255) & ~(size_t)255;
        return r;
    };
    unsigned short* PG   = (unsigned short*)alloc((size_t)NTOT * GW * 2);   // 111.8 MB
    float*          C    = (float*)alloc((size_t)NTOT * MEM * 4);           //  52.4 MB
    unsigned short* Hbf  = (unsigned short*)alloc((size_t)NTOT * KH * 2);   //  28.0 MB
    unsigned short* W4xT = (unsigned short*)alloc((size_t)GW * KXP * 2);
    unsigned short* W4hT = (unsigned short*)alloc((size_t)GW * KH * 2);
    float*          b4x  = (float*)alloc(GW * 4);
    float*          b4hf = (float*)alloc(GW * 4);
    if ((size_t)(p - (char*)d_ws) > ws_size) return;

    // Abf (bf16 embs, NTOT*KXP = 55.9 MB) aliases PG's LEAF region (bytes
    // [0, 83.9 MB)): the x-proj GEMM reads Abf while writing only internal PG
    // rows (byte offset >= NLEAF*GW*2 = 83.9 MB); leaf cells go direct to
    // out/C/Hbf. The leaf PG region is otherwise dead.
    unsigned short* Abf = PG;

    {
        int convBlocks = (NTOT * (KXP / 8) + 255) / 256;
        prep<<<256 + convBlocks, 256, 0, stream>>>(
            Wix, Wfx, Wux, Wox, bix, bfx, bux, box,
            Wih, Wfh, Wuh, Woh, bfh, embs,
            W4xT, W4hT, b4x, b4hf, Abf);
    }

    // x-projections for ALL nodes; leaf cells fused in-epilogue
    {
        int mt = (NTOT + 127) / 128;
        gemm_xproj<<<mt * 5, 512, 0, stream>>>(
            Abf, W4xT, b4x, PG, bih, buh, boh, out, C, Hbf);
    }

    // levels: one fused GEMM+cell dispatch each
    for (int d = 1; d < DEPTH; ++d) {
        int nprev = SIZES[d - 1];
        int n = SIZES[d];
        int mt = (nprev + 127) / 128;
        gemm_level<<<mt * 5, 512, 0, stream>>>(
            Hbf + (size_t)OFF[d - 1] * KH, nprev, n,
            W4hT, b4hf,
            PG + (size_t)OFF[d] * GW,
            C + (size_t)OFF[d - 1] * MEM,
            bih, buh, boh,
            out + (size_t)OFF[d] * MEM, C + (size_t)OFF[d] * MEM,
            Hbf + (size_t)OFF[d] * KH);
    }
}